// Round 1
// baseline (194.070 us; speedup 1.0000x reference)
//
#include <hip/hip_runtime.h>

// Problem constants (AdditiveAttention): B=4, Q=256, K=1024, DQ=DK=DV=512, H=128
#define B_ 4
#define Q_ 256
#define K_ 1024
#define D_ 512
#define H_ 128
#define DV_ 512

// tanh(x) where input is pre-scaled by 2*log2(e):  tanh = 1 - 2/(exp2(x2l)+1)
__device__ __forceinline__ float tanh_e(float x2l) {
    float e = __builtin_amdgcn_exp2f(x2l);
    return 1.0f - 2.0f * __builtin_amdgcn_rcpf(e + 1.0f);
}

// ---------------------------------------------------------------------------
// Kernel 1: projections.
//   qh_s[row][h]   = 2*log2e * sum_d q[row][d]*w_q[h][d]      row in [0, B*Q)
//   kh_t[b][h][kk] = 2*log2e * sum_d k[b,kk][d]*w_k[h][d]     (transposed!)
// One block = 8 input rows x all 128 h. 256 threads: h = t&127, 4 rows each.
// ---------------------------------------------------------------------------
__global__ __launch_bounds__(256) void proj_kernel(
    const float* __restrict__ qin, const float* __restrict__ kin,
    const float* __restrict__ wq,  const float* __restrict__ wk,
    float* __restrict__ qh_s, float* __restrict__ kh_t)
{
    __shared__ float4 xs[1024];               // 8 rows x 128 float4 = 16 KB
    const int t   = threadIdx.x;
    const int bid = blockIdx.x;

    const float4* X;
    const float4* W;
    int rowsBase;
    const bool isQ = (bid < (B_*Q_/8));       // 128 q-blocks, then 512 k-blocks
    if (isQ) { X = (const float4*)qin; W = (const float4*)wq; rowsBase = bid * 8; }
    else     { X = (const float4*)kin; W = (const float4*)wk; rowsBase = (bid - B_*Q_/8) * 8; }

    const float4* Xb = X + rowsBase * (D_/4);
#pragma unroll
    for (int i = 0; i < 4; ++i) xs[t + i*256] = Xb[t + i*256];
    __syncthreads();

    const int h  = t & 127;
    const int r0 = (t >> 7) * 4;              // rows r0..r0+3
    float a0 = 0.f, a1 = 0.f, a2 = 0.f, a3 = 0.f;
    const float4* wrow = W + h * (D_/4);
#pragma unroll 4
    for (int d = 0; d < D_/4; ++d) {
        float4 wv = wrow[d];
        float4 x0 = xs[(r0+0)*128 + d];
        float4 x1 = xs[(r0+1)*128 + d];
        float4 x2 = xs[(r0+2)*128 + d];
        float4 x3 = xs[(r0+3)*128 + d];
        a0 += wv.x*x0.x + wv.y*x0.y + wv.z*x0.z + wv.w*x0.w;
        a1 += wv.x*x1.x + wv.y*x1.y + wv.z*x1.z + wv.w*x1.w;
        a2 += wv.x*x2.x + wv.y*x2.y + wv.z*x2.z + wv.w*x2.w;
        a3 += wv.x*x3.x + wv.y*x3.y + wv.z*x3.z + wv.w*x3.w;
    }
    const float S = 2.885390081777927f;       // 2*log2(e)
    float vals[4] = {a0*S, a1*S, a2*S, a3*S};
    if (isQ) {
#pragma unroll
        for (int i = 0; i < 4; ++i) {
            int row = rowsBase + r0 + i;                    // [0, B*Q)
            qh_s[row*H_ + h] = vals[i];
        }
    } else {
#pragma unroll
        for (int i = 0; i < 4; ++i) {
            int row = rowsBase + r0 + i;                    // [0, B*K)
            int b = row >> 10, kk = row & 1023;
            kh_t[(b*H_ + h)*K_ + kk] = vals[i];
        }
    }
}

// ---------------------------------------------------------------------------
// Kernel 2: fused scores + masked softmax + attn@v.
// Grid: 256 blocks = B * (Q/4); block = 512 threads (8 waves), 1 block/CU.
// Phase B: thread owns k = {t, t+512}, accumulates 4 q-scores each.
// Phase C: waves 0..3 do softmax for their q-row (invalid k -> exp == 0,
//          identical to reference's -1e6 fill which underflows to 0).
// Phase D: thread-half g covers k in [g*512, g*512+512); dv = float2 at t&255.
// ---------------------------------------------------------------------------
__global__ __launch_bounds__(512) void attn_kernel(
    const float* __restrict__ qh_s, const float* __restrict__ kh_t,
    const float* __restrict__ v,    const float* __restrict__ wvg,
    const int* __restrict__ valid_lens, float* __restrict__ out)
{
    __shared__ float  qv[4*128];
    __shared__ float  wv[128];
    __shared__ float  p[4][1024];
    __shared__ float  rstat[4];
    __shared__ float2 obuf[4][256];

    const int t   = threadIdx.x;
    const int bid = blockIdx.x;               // [0, 256)
    const int b   = bid >> 6;
    const int q0  = (bid & 63) * 4;

    // Phase A: stage q-tile rows (512 floats) and w_v
    qv[t] = qh_s[(b*Q_ + q0)*H_ + t];
    if (t < 128) wv[t] = wvg[t];
    __syncthreads();

    const int vl = valid_lens[b];

    // ---- Phase B: scores ----
    const float* khb = kh_t + b * H_ * K_;
    float acc[4][2] = {};
    for (int h = 0; h < H_; h += 4) {
        float4 wv4 = *(const float4*)&wv[h];
        float4 q4[4];
#pragma unroll
        for (int qi = 0; qi < 4; ++qi) q4[qi] = *(const float4*)&qv[qi*128 + h];
#pragma unroll
        for (int hh = 0; hh < 4; ++hh) {
            const float* khr = khb + (h + hh) * K_;
            float ka = khr[t];
            float kb = khr[t + 512];
            float w  = ((const float*)&wv4)[hh];
#pragma unroll
            for (int qi = 0; qi < 4; ++qi) {
                float qq = ((const float*)&q4[qi])[hh];
                acc[qi][0] += w * tanh_e(qq + ka);
                acc[qi][1] += w * tanh_e(qq + kb);
            }
        }
    }
#pragma unroll
    for (int qi = 0; qi < 4; ++qi) { p[qi][t] = acc[qi][0]; p[qi][t + 512] = acc[qi][1]; }
    __syncthreads();

    // ---- Phase C: masked softmax (waves 0..3, one q-row each) ----
    const int wid = t >> 6, lane = t & 63;
    if (wid < 4) {
        float* row = p[wid];
        float m = -3.0e38f;
#pragma unroll
        for (int i = 0; i < 16; ++i) {
            int k = lane + i*64;
            float s = row[k];
            if (k < vl) m = fmaxf(m, s);
        }
#pragma unroll
        for (int off = 32; off > 0; off >>= 1) m = fmaxf(m, __shfl_xor(m, off));
        float ssum = 0.f;
#pragma unroll
        for (int i = 0; i < 16; ++i) {
            int k = lane + i*64;
            float e = 0.f;
            if (k < vl) e = __builtin_amdgcn_exp2f((row[k] - m) * 1.4426950408889634f);
            row[k] = e;
            ssum += e;
        }
#pragma unroll
        for (int off = 32; off > 0; off >>= 1) ssum += __shfl_xor(ssum, off);
        if (lane == 0) rstat[wid] = __builtin_amdgcn_rcpf(ssum);
    }
    __syncthreads();

    // ---- Phase D: attn @ v ----
    const int g  = t >> 8;                    // k-range half
    const int tt = t & 255;                   // float2 column
    const float2* vb = (const float2*)(v + (size_t)b * K_ * DV_);
    float2 o[4];
#pragma unroll
    for (int qi = 0; qi < 4; ++qi) { o[qi].x = 0.f; o[qi].y = 0.f; }

    const int kbeg = g * 512;
    const int kend = (vl < kbeg + 512) ? vl : (kbeg + 512);
    int k = kbeg;
    for (; k + 3 < kend; k += 4) {
        float2 v0 = vb[(k+0)*256 + tt];
        float2 v1 = vb[(k+1)*256 + tt];
        float2 v2 = vb[(k+2)*256 + tt];
        float2 v3 = vb[(k+3)*256 + tt];
#pragma unroll
        for (int qi = 0; qi < 4; ++qi) {
            float4 pq = *(const float4*)&p[qi][k];
            o[qi].x += pq.x*v0.x + pq.y*v1.x + pq.z*v2.x + pq.w*v3.x;
            o[qi].y += pq.x*v0.y + pq.y*v1.y + pq.z*v2.y + pq.w*v3.y;
        }
    }
    for (; k < kend; ++k) {
        float2 v0 = vb[k*256 + tt];
#pragma unroll
        for (int qi = 0; qi < 4; ++qi) {
            float pk = p[qi][k];
            o[qi].x += pk*v0.x;
            o[qi].y += pk*v0.y;
        }
    }

    if (g == 1) {
#pragma unroll
        for (int qi = 0; qi < 4; ++qi) obuf[qi][tt] = o[qi];
    }
    __syncthreads();
    if (g == 0) {
#pragma unroll
        for (int qi = 0; qi < 4; ++qi) {
            float rs = rstat[qi];
            float2 ov = obuf[qi][tt];
            float2 res;
            res.x = (o[qi].x + ov.x) * rs;
            res.y = (o[qi].y + ov.y) * rs;
            ((float2*)(out + (size_t)(b*Q_ + q0 + qi) * DV_))[tt] = res;
        }
    }
}

extern "C" void kernel_launch(void* const* d_in, const int* in_sizes, int n_in,
                              void* d_out, int out_size, void* d_ws, size_t ws_size,
                              hipStream_t stream)
{
    const float* q  = (const float*)d_in[0];
    const float* k  = (const float*)d_in[1];
    const float* v  = (const float*)d_in[2];
    const int*   vl = (const int*)d_in[3];
    const float* wq = (const float*)d_in[4];
    const float* wk = (const float*)d_in[5];
    const float* wv = (const float*)d_in[6];
    float* out = (float*)d_out;

    float* qh_s = (float*)d_ws;               // B*Q*H  = 131072 floats
    float* kh_t = qh_s + B_*Q_*H_;            // B*H*K  = 524288 floats

    proj_kernel<<<dim3(B_*Q_/8 + B_*K_/8), dim3(256), 0, stream>>>(q, k, wq, wk, qh_s, kh_t);
    attn_kernel<<<dim3(B_ * (Q_/4)), dim3(512), 0, stream>>>(qh_s, kh_t, v, wv, vl, out);
}

// Round 2
// 149.568 us; speedup vs baseline: 1.2975x; 1.2975x over previous
//
#include <hip/hip_runtime.h>

// AdditiveAttention: B=4, Q=256, K=1024, DQ=DK=DV=512, H=128
#define B_ 4
#define Q_ 256
#define K_ 1024
#define D_ 512
#define H_ 128
#define DV_ 512
#define SCALE 2.885390081777927f   // 2*log2(e): tanh(x)=1-2/(exp2(S*x)+1)
#define LOG2E 1.4426950408889634f

__device__ __forceinline__ float tanh_e(float x2l) {
    float e = __builtin_amdgcn_exp2f(x2l);
    return 1.0f - 2.0f * __builtin_amdgcn_rcpf(e + 1.0f);
}

// ---------------------------------------------------------------------------
// zero d_out (poisoned 0xAA each run; PV accumulates with atomicAdd)
// ---------------------------------------------------------------------------
__global__ __launch_bounds__(512) void zero_kernel(float4* __restrict__ out) {
    out[blockIdx.x * 512 + threadIdx.x] = make_float4(0.f, 0.f, 0.f, 0.f);
}

// ---------------------------------------------------------------------------
// proj: tiled GEMM, 16 rows x 128 h per block, BK=32, 256 thr, micro 2x4.
//   qh_s[row][h]        = S * q[row]·w_q[h]          (64 blocks)
//   kh4[b][h>>2][k][h&3]= S * k[b,k]·w_k[h]          (256 blocks, coalesced
//                                                     float4-of-4h for scores)
// k-blocks fully beyond valid_len are skipped (their kh is never read).
// ---------------------------------------------------------------------------
__global__ __launch_bounds__(256) void proj_kernel(
    const float* __restrict__ qin, const float* __restrict__ kin,
    const float* __restrict__ wq,  const float* __restrict__ wk,
    const int* __restrict__ valid_lens,
    float* __restrict__ qh_s, float* __restrict__ kh4)
{
    __shared__ float Xs[32][20];    // [kk][row], stride 80B (16B-aligned rows)
    __shared__ float Ws[32][132];   // [kk][h],   stride 528B

    const int t   = threadIdx.x;
    const int bid = blockIdx.x;
    const bool isQ = bid < (B_*Q_/16);          // 64 q-blocks, then 256 k-blocks
    const float* X; const float* W; int R0;
    if (isQ) { X = qin; W = wq; R0 = bid * 16; }
    else {
        X = kin; W = wk; R0 = (bid - B_*Q_/16) * 16;
        if ((R0 & 1023) >= valid_lens[R0 >> 10]) return;  // block-uniform
    }

    const int tx = t & 31, ty = t >> 5;
    const int h0 = tx * 4, r0 = ty * 2;
    float c[2][4] = {};

    for (int d0 = 0; d0 < D_; d0 += 32) {
        if (t < 128) {
            int row = t >> 3, dd = (t & 7) * 4;
            float4 xv = *(const float4*)&X[(size_t)(R0 + row) * D_ + d0 + dd];
            Xs[dd+0][row] = xv.x; Xs[dd+1][row] = xv.y;
            Xs[dd+2][row] = xv.z; Xs[dd+3][row] = xv.w;
        }
#pragma unroll
        for (int i = 0; i < 4; ++i) {
            int h = (t >> 3) + i * 32, dd = (t & 7) * 4;
            float4 wv4 = *(const float4*)&W[(size_t)h * D_ + d0 + dd];
            Ws[dd+0][h] = wv4.x; Ws[dd+1][h] = wv4.y;
            Ws[dd+2][h] = wv4.z; Ws[dd+3][h] = wv4.w;
        }
        __syncthreads();
#pragma unroll
        for (int kk = 0; kk < 32; ++kk) {
            float2 xv = *(const float2*)&Xs[kk][r0];
            float4 w4 = *(const float4*)&Ws[kk][h0];
            c[0][0] += xv.x * w4.x; c[0][1] += xv.x * w4.y;
            c[0][2] += xv.x * w4.z; c[0][3] += xv.x * w4.w;
            c[1][0] += xv.y * w4.x; c[1][1] += xv.y * w4.y;
            c[1][2] += xv.y * w4.z; c[1][3] += xv.y * w4.w;
        }
        __syncthreads();
    }

    if (isQ) {
#pragma unroll
        for (int i = 0; i < 2; ++i) {
            float4 o = make_float4(c[i][0]*SCALE, c[i][1]*SCALE, c[i][2]*SCALE, c[i][3]*SCALE);
            *(float4*)&qh_s[(size_t)(R0 + r0 + i) * H_ + h0] = o;
        }
    } else {
        const int b = R0 >> 10;
#pragma unroll
        for (int i = 0; i < 2; ++i) {
            int kk = (R0 & 1023) + r0 + i;
            float4 o = make_float4(c[i][0]*SCALE, c[i][1]*SCALE, c[i][2]*SCALE, c[i][3]*SCALE);
            *(float4*)&kh4[((size_t)(b * 32 + tx) * K_ + kk) * 4] = o;
        }
    }
}

// ---------------------------------------------------------------------------
// scores + masked softmax. 512 blocks = B x Q/2, 512 threads (2 blocks/CU,
// 16 waves/CU). Thread owns k = {t, t+512}; masked k-columns skip the whole
// tanh loop (exp(-1e6-m) == 0 exactly, so this is bit-equivalent).
// Writes unnormalized exp to p_ws and 1/sum to rs_ws.
// ---------------------------------------------------------------------------
__global__ __launch_bounds__(512) void scores_kernel(
    const float* __restrict__ qh_s, const float* __restrict__ kh4,
    const float* __restrict__ wvg,  const int* __restrict__ valid_lens,
    float* __restrict__ p_ws, float* __restrict__ rs_ws)
{
    __shared__ float qv[256];
    __shared__ float wvs[128];
    __shared__ float p[2][1024];
    __shared__ float red[8];

    const int t   = threadIdx.x;
    const int bid = blockIdx.x;
    const int b   = bid >> 7;
    const int q0  = (bid & 127) * 2;

    if (t < 256)      qv[t] = qh_s[(size_t)(b*Q_ + q0) * H_ + t];
    else if (t < 384) wvs[t-256] = wvg[t-256];
    __syncthreads();

    const int vl = valid_lens[b];
    const float* khb = kh4 + (size_t)b * 32 * K_ * 4;

    float a00 = 0.f, a01 = 0.f, a10 = 0.f, a11 = 0.f;
    if (t < vl) {
        for (int hq = 0; hq < 32; ++hq) {
            float4 kx = *(const float4*)&khb[(size_t)hq * K_ * 4 + t * 4];
            float4 w4 = *(const float4*)&wvs[hq*4];
            float4 qa = *(const float4*)&qv[hq*4];
            float4 qb = *(const float4*)&qv[128 + hq*4];
            a00 += w4.x*tanh_e(qa.x+kx.x) + w4.y*tanh_e(qa.y+kx.y)
                 + w4.z*tanh_e(qa.z+kx.z) + w4.w*tanh_e(qa.w+kx.w);
            a01 += w4.x*tanh_e(qb.x+kx.x) + w4.y*tanh_e(qb.y+kx.y)
                 + w4.z*tanh_e(qb.z+kx.z) + w4.w*tanh_e(qb.w+kx.w);
        }
    }
    if (t + 512 < vl) {
        for (int hq = 0; hq < 32; ++hq) {
            float4 kx = *(const float4*)&khb[(size_t)hq * K_ * 4 + (t+512) * 4];
            float4 w4 = *(const float4*)&wvs[hq*4];
            float4 qa = *(const float4*)&qv[hq*4];
            float4 qb = *(const float4*)&qv[128 + hq*4];
            a10 += w4.x*tanh_e(qa.x+kx.x) + w4.y*tanh_e(qa.y+kx.y)
                 + w4.z*tanh_e(qa.z+kx.z) + w4.w*tanh_e(qa.w+kx.w);
            a11 += w4.x*tanh_e(qb.x+kx.x) + w4.y*tanh_e(qb.y+kx.y)
                 + w4.z*tanh_e(qb.z+kx.z) + w4.w*tanh_e(qb.w+kx.w);
        }
    }
    p[0][t] = a00; p[1][t] = a01; p[0][t+512] = a10; p[1][t+512] = a11;
    __syncthreads();

    // softmax: 8 waves, wave w -> row w>>2, quarter w&3 (256 elems as float4)
    const int wid = t >> 6, lane = t & 63;
    const int row = wid >> 2, seg = wid & 3;
    const int kb  = seg * 256 + lane * 4;
    float4 s4 = *(const float4*)&p[row][kb];
    float m = -3.0e38f;
    if (kb + 0 < vl) m = fmaxf(m, s4.x);
    if (kb + 1 < vl) m = fmaxf(m, s4.y);
    if (kb + 2 < vl) m = fmaxf(m, s4.z);
    if (kb + 3 < vl) m = fmaxf(m, s4.w);
#pragma unroll
    for (int off = 32; off > 0; off >>= 1) m = fmaxf(m, __shfl_xor(m, off));
    if (lane == 0) red[wid] = m;
    __syncthreads();
    m = fmaxf(fmaxf(red[row*4+0], red[row*4+1]), fmaxf(red[row*4+2], red[row*4+3]));

    float4 e4;
    e4.x = (kb + 0 < vl) ? __builtin_amdgcn_exp2f((s4.x - m) * LOG2E) : 0.f;
    e4.y = (kb + 1 < vl) ? __builtin_amdgcn_exp2f((s4.y - m) * LOG2E) : 0.f;
    e4.z = (kb + 2 < vl) ? __builtin_amdgcn_exp2f((s4.z - m) * LOG2E) : 0.f;
    e4.w = (kb + 3 < vl) ? __builtin_amdgcn_exp2f((s4.w - m) * LOG2E) : 0.f;
    float sum = e4.x + e4.y + e4.z + e4.w;
#pragma unroll
    for (int off = 32; off > 0; off >>= 1) sum += __shfl_xor(sum, off);
    __syncthreads();
    if (lane == 0) red[wid] = sum;
    __syncthreads();
    float tot = red[row*4+0] + red[row*4+1] + red[row*4+2] + red[row*4+3];

    *(float4*)&p_ws[(size_t)(b*Q_ + q0 + row) * K_ + kb] = e4;
    if (lane == 0 && seg == 0)
        rs_ws[b*Q_ + q0 + row] = __builtin_amdgcn_rcpf(tot);
}

// ---------------------------------------------------------------------------
// PV: tiled GEMM out[b,q,dv] += (p/sum)·v. Tile 32q x 128dv x 512k-half,
// BK=32, 256 thr, micro 4x4. Grid 4b x 8qt x 4dvt x 2kh = 256 blocks.
// Output pre-zeroed; halves combine via atomicAdd. Chunks past valid_len
// skipped (p there is exactly 0 anyway).
// ---------------------------------------------------------------------------
__global__ __launch_bounds__(256) void pv_kernel(
    const float* __restrict__ p_ws, const float* __restrict__ vin,
    const float* __restrict__ rs_ws, const int* __restrict__ valid_lens,
    float* __restrict__ out)
{
    __shared__ float Ps[32][36];    // [kk][q]
    __shared__ float Vs[32][132];   // [kk][dv]

    const int t   = threadIdx.x;
    const int bid = blockIdx.x;
    const int kh  = bid & 1, dvt = (bid >> 1) & 3, qt = (bid >> 3) & 7, b = bid >> 6;
    const int Q0 = qt * 32, DV0 = dvt * 128, Kbase = kh * 512;

    const int vl = valid_lens[b];
    if (Kbase >= vl) return;                     // block-uniform, before barriers
    const int klen = min(512, vl - Kbase);
    const int nch  = (klen + 31) >> 5;

    const int tx = t & 31, ty = t >> 5;
    const int dv0 = tx * 4, r0 = ty * 4;
    float c[4][4] = {};

    for (int ch = 0; ch < nch; ++ch) {
        const int kc = Kbase + ch * 32;
        {
            int qq = t >> 3, kkd = (t & 7) * 4;
            float4 pv4 = *(const float4*)&p_ws[(size_t)(b*Q_ + Q0 + qq) * K_ + kc + kkd];
            Ps[kkd+0][qq] = pv4.x; Ps[kkd+1][qq] = pv4.y;
            Ps[kkd+2][qq] = pv4.z; Ps[kkd+3][qq] = pv4.w;
        }
#pragma unroll
        for (int i = 0; i < 4; ++i) {
            int kk = (t >> 5) + i * 8, dvd = (t & 31) * 4;
            *(float4*)&Vs[kk][dvd] =
                *(const float4*)&vin[(size_t)(b*K_ + kc + kk) * DV_ + DV0 + dvd];
        }
        __syncthreads();
#pragma unroll
        for (int kk = 0; kk < 32; ++kk) {
            float4 pf = *(const float4*)&Ps[kk][r0];
            float4 vf = *(const float4*)&Vs[kk][dv0];
            c[0][0] += pf.x*vf.x; c[0][1] += pf.x*vf.y; c[0][2] += pf.x*vf.z; c[0][3] += pf.x*vf.w;
            c[1][0] += pf.y*vf.x; c[1][1] += pf.y*vf.y; c[1][2] += pf.y*vf.z; c[1][3] += pf.y*vf.w;
            c[2][0] += pf.z*vf.x; c[2][1] += pf.z*vf.y; c[2][2] += pf.z*vf.z; c[2][3] += pf.z*vf.w;
            c[3][0] += pf.w*vf.x; c[3][1] += pf.w*vf.y; c[3][2] += pf.w*vf.z; c[3][3] += pf.w*vf.w;
        }
        __syncthreads();
    }

#pragma unroll
    for (int i = 0; i < 4; ++i) {
        float rs = rs_ws[b*Q_ + Q0 + r0 + i];
        float* orow = &out[(size_t)(b*Q_ + Q0 + r0 + i) * DV_ + DV0 + dv0];
        atomicAdd(&orow[0], c[i][0] * rs);
        atomicAdd(&orow[1], c[i][1] * rs);
        atomicAdd(&orow[2], c[i][2] * rs);
        atomicAdd(&orow[3], c[i][3] * rs);
    }
}

extern "C" void kernel_launch(void* const* d_in, const int* in_sizes, int n_in,
                              void* d_out, int out_size, void* d_ws, size_t ws_size,
                              hipStream_t stream)
{
    const float* q  = (const float*)d_in[0];
    const float* k  = (const float*)d_in[1];
    const float* v  = (const float*)d_in[2];
    const int*   vl = (const int*)d_in[3];
    const float* wq = (const float*)d_in[4];
    const float* wk = (const float*)d_in[5];
    const float* wv = (const float*)d_in[6];
    float* out = (float*)d_out;

    float* qh_s = (float*)d_ws;                       //  131072 floats
    float* kh4  = qh_s + (size_t)B_*Q_*H_;            //  524288 floats
    float* p_ws = kh4  + (size_t)B_*H_*K_;            // 1048576 floats
    float* rs_ws= p_ws + (size_t)B_*Q_*K_;            //    1024 floats

    zero_kernel  <<<dim3(256), dim3(512), 0, stream>>>((float4*)out);
    proj_kernel  <<<dim3(64 + 256), dim3(256), 0, stream>>>(q, k, wq, wk, vl, qh_s, kh4);
    scores_kernel<<<dim3(512), dim3(512), 0, stream>>>(qh_s, kh4, wv, vl, p_ws, rs_ws);
    pv_kernel    <<<dim3(256), dim3(256), 0, stream>>>(p_ws, v, rs_ws, vl, out);
}